// Round 1
// baseline (275.895 us; speedup 1.0000x reference)
//
#include <hip/hip_runtime.h>

#define NUM_JOINTS 24
#define NUM_VERTS  6890
#define NUM_COORDS (NUM_VERTS * 3)   // 20670
#define NUM_BETAS  10
#define KTOT       217               // 10 betas + 207 pose features
#define BATCH      512

// ---- ws layout (floats) ----
// SJ:  [0,720)      SJ[k][j][c] = sum_v Jr[v][j] * shapedirs[k][v*3+c]
// JT:  [720,792)    JT[j][c]    = sum_v Jr[v][j] * v_template[v][c]
// A:   [800, 800+512*24*12)
// XT:  [148256, 148256+217*512)
// wT:  [259360, 259360+24*6912)
#define WS_SJ 0
#define WS_JT 720
#define WS_A  800
#define WS_XT 148256
#define WS_WT 259360
#define WT_STRIDE 6912

// ---------------- Kernel 1: fold J_regressor into SJ / JT ----------------
__global__ __launch_bounds__(256) void reduce_sj(const float* __restrict__ Jr,
                                                 const float* __restrict__ sd,
                                                 const float* __restrict__ vt,
                                                 float* __restrict__ ws) {
    const int s = blockIdx.x;   // 0..32: 0..29 -> shapedirs (k=s/3,c=s%3), 30..32 -> v_template (c=s-30)
    const int j = blockIdx.y;   // 0..23
    const int tid = threadIdx.x;
    float sum = 0.f;
    if (s < 30) {
        const int k = s / 3, c = s % 3;
        const float* src = sd + k * NUM_COORDS;
        for (int v = tid; v < NUM_VERTS; v += 256)
            sum += Jr[v * 24 + j] * src[v * 3 + c];
    } else {
        const int c = s - 30;
        for (int v = tid; v < NUM_VERTS; v += 256)
            sum += Jr[v * 24 + j] * vt[v * 3 + c];
    }
    __shared__ float red[256];
    red[tid] = sum;
    __syncthreads();
    for (int off = 128; off > 0; off >>= 1) {
        if (tid < off) red[tid] += red[tid + off];
        __syncthreads();
    }
    if (tid == 0) {
        if (s < 30) ws[WS_SJ + (s / 3) * 72 + j * 3 + (s % 3)] = red[0];
        else        ws[WS_JT + j * 3 + (s - 30)] = red[0];
    }
}

// ---------------- Kernel 1b: transpose lbs_weights -> wT[24][6912] ----------------
__global__ __launch_bounds__(256) void transpose_w(const float* __restrict__ w,
                                                   float* __restrict__ wT) {
    const int v = blockIdx.x * 256 + threadIdx.x;   // < 6912
    const int j = blockIdx.y;
    wT[j * WT_STRIDE + v] = (v < NUM_VERTS) ? w[v * 24 + j] : 0.f;
}

// ---------------- Kernel 2: per-batch Rodrigues + joints + kinematic chain ----------------
__global__ __launch_bounds__(64) void per_batch(const float* __restrict__ x,
                                                const int* __restrict__ parents,
                                                const float* __restrict__ ws_sj,
                                                float* __restrict__ ws_A,
                                                float* __restrict__ ws_XT) {
    const int b = blockIdx.x;
    const int tid = threadIdx.x;
    __shared__ float Rs[24][9], Jl[24][3], Rg[24][9], tg[24][3];
    const float* row = x + b * (NUM_BETAS + 72);

    if (tid < 24) {
        const int j = tid;
        const float t0 = row[3 * j + 0], t1 = row[3 * j + 1], t2 = row[3 * j + 2];
        const float a0 = t0 + 1e-8f, a1 = t1 + 1e-8f, a2 = t2 + 1e-8f;
        const float angle = sqrtf(a0 * a0 + a1 * a1 + a2 * a2);
        const float inv = 1.0f / angle;
        const float rx = t0 * inv, ry = t1 * inv, rz = t2 * inv;
        const float c = cosf(angle), sn = sinf(angle), o = 1.f - c;
        float R[9];
        R[0] = c + o * rx * rx;      R[1] = o * rx * ry - sn * rz; R[2] = o * rx * rz + sn * ry;
        R[3] = o * rx * ry + sn * rz; R[4] = c + o * ry * ry;      R[5] = o * ry * rz - sn * rx;
        R[6] = o * rx * rz - sn * ry; R[7] = o * ry * rz + sn * rx; R[8] = c + o * rz * rz;
        #pragma unroll
        for (int i = 0; i < 9; ++i) Rs[j][i] = R[i];
        // joint positions: J[j][c] = JT[j][c] + sum_k betas[k]*SJ[k][j][c]
        #pragma unroll
        for (int c3 = 0; c3 < 3; ++c3) {
            float s = ws_sj[WS_JT + j * 3 + c3];
            #pragma unroll
            for (int k = 0; k < NUM_BETAS; ++k)
                s += row[72 + k] * ws_sj[WS_SJ + k * 72 + j * 3 + c3];
            Jl[j][c3] = s;
        }
        // pose features into XT rows 10..216
        if (j >= 1) {
            #pragma unroll
            for (int i = 0; i < 9; ++i) {
                const float pf = R[i] - ((i == 0 || i == 4 || i == 8) ? 1.f : 0.f);
                ws_XT[(10 + (j - 1) * 9 + i) * BATCH + b] = pf;
            }
        }
    }
    if (tid < NUM_BETAS) ws_XT[tid * BATCH + b] = row[72 + tid];
    __syncthreads();

    if (tid == 0) {
        #pragma unroll
        for (int i = 0; i < 9; ++i) Rg[0][i] = Rs[0][i];
        #pragma unroll
        for (int c3 = 0; c3 < 3; ++c3) tg[0][c3] = Jl[0][c3];
        for (int i = 1; i < 24; ++i) {
            const int p = parents[i];
            float tmp[9];
            #pragma unroll
            for (int r = 0; r < 3; ++r)
                #pragma unroll
                for (int cc = 0; cc < 3; ++cc)
                    tmp[r * 3 + cc] = Rg[p][r * 3 + 0] * Rs[i][0 + cc] +
                                      Rg[p][r * 3 + 1] * Rs[i][3 + cc] +
                                      Rg[p][r * 3 + 2] * Rs[i][6 + cc];
            #pragma unroll
            for (int q = 0; q < 9; ++q) Rg[i][q] = tmp[q];
            const float tr0 = Jl[i][0] - Jl[p][0];
            const float tr1 = Jl[i][1] - Jl[p][1];
            const float tr2 = Jl[i][2] - Jl[p][2];
            #pragma unroll
            for (int r = 0; r < 3; ++r)
                tg[i][r] = Rg[p][r * 3 + 0] * tr0 + Rg[p][r * 3 + 1] * tr1 +
                           Rg[p][r * 3 + 2] * tr2 + tg[p][r];
        }
    }
    __syncthreads();

    if (tid < 24) {
        const int j = tid;
        float* Ab = ws_A + (b * 24 + j) * 12;
        #pragma unroll
        for (int r = 0; r < 3; ++r) {
            const float t = tg[j][r] - (Rg[j][r * 3 + 0] * Jl[j][0] +
                                        Rg[j][r * 3 + 1] * Jl[j][1] +
                                        Rg[j][r * 3 + 2] * Jl[j][2]);
            Ab[r * 4 + 0] = Rg[j][r * 3 + 0];
            Ab[r * 4 + 1] = Rg[j][r * 3 + 1];
            Ab[r * 4 + 2] = Rg[j][r * 3 + 2];
            Ab[r * 4 + 3] = t;
        }
    }
}

// ---------------- Kernel 3a: v_posed = X @ D + v_template  -> d_out ----------------
// block: 256 threads, tile 64 batches x 64 verts; thread: 4 batches x 4 verts
#define KC 31
__global__ __launch_bounds__(256) void gemm_vposed(const float* __restrict__ sd,
                                                   const float* __restrict__ pd,
                                                   const float* __restrict__ vt,
                                                   const float* __restrict__ XT,
                                                   float* __restrict__ out) {
    __shared__ float Ds[KC][192];
    __shared__ float Xs[KC][64];
    const int v0 = blockIdx.x * 64;       // vertex tile base
    const int b0 = blockIdx.y * 64;       // batch tile base
    const int tid = threadIdx.x;
    const int tx = tid & 15;              // vert group  (4 verts = 12 coords)
    const int ty = tid >> 4;              // batch group (4 batches)

    float acc[4][12];
    #pragma unroll
    for (int m = 0; m < 4; ++m)
        #pragma unroll
        for (int i = 0; i < 12; ++i) acc[m][i] = 0.f;

    for (int k0 = 0; k0 < KTOT; k0 += KC) {
        __syncthreads();
        // stage D chunk: KC x 192 floats as float2 (D rows are only 8B-aligned)
        #pragma unroll
        for (int e = 0; e < 12; ++e) {
            const int e2 = tid + e * 256;
            if (e2 < KC * 96) {
                const int k = e2 / 96;
                const int c2 = (e2 % 96) * 2;
                const int kg = k0 + k;
                const float* Drow = (kg < 10) ? (sd + kg * NUM_COORDS)
                                              : (pd + (kg - 10) * NUM_COORDS);
                const int g = v0 * 3 + c2;
                float2 val;
                if (g < NUM_COORDS) val = *(const float2*)(Drow + g);
                else { val.x = 0.f; val.y = 0.f; }
                *(float2*)(&Ds[k][c2]) = val;
            }
        }
        // stage X chunk: KC x 64 floats (XT is ours, 16B aligned)
        #pragma unroll
        for (int e = 0; e < 2; ++e) {
            const int e4 = tid + e * 256;
            if (e4 < KC * 16) {
                const int k = e4 >> 4;
                const int b4 = (e4 & 15) * 4;
                *(float4*)(&Xs[k][b4]) = *(const float4*)(XT + (k0 + k) * BATCH + b0 + b4);
            }
        }
        __syncthreads();

        for (int k = 0; k < KC; ++k) {
            const float4 xv = *(float4*)(&Xs[k][ty * 4]);
            const float4 d0 = *(float4*)(&Ds[k][tx * 12 + 0]);
            const float4 d1 = *(float4*)(&Ds[k][tx * 12 + 4]);
            const float4 d2 = *(float4*)(&Ds[k][tx * 12 + 8]);
            const float xm[4] = {xv.x, xv.y, xv.z, xv.w};
            #pragma unroll
            for (int m = 0; m < 4; ++m) {
                acc[m][0]  += xm[m] * d0.x; acc[m][1]  += xm[m] * d0.y;
                acc[m][2]  += xm[m] * d0.z; acc[m][3]  += xm[m] * d0.w;
                acc[m][4]  += xm[m] * d1.x; acc[m][5]  += xm[m] * d1.y;
                acc[m][6]  += xm[m] * d1.z; acc[m][7]  += xm[m] * d1.w;
                acc[m][8]  += xm[m] * d2.x; acc[m][9]  += xm[m] * d2.y;
                acc[m][10] += xm[m] * d2.z; acc[m][11] += xm[m] * d2.w;
            }
        }
    }

    // epilogue: + v_template, store (float2: rows only 8B aligned)
    const int gbase = v0 * 3 + tx * 12;
    float vtl[12];
    #pragma unroll
    for (int i = 0; i < 12; ++i)
        vtl[i] = (gbase + i < NUM_COORDS) ? vt[gbase + i] : 0.f;
    #pragma unroll
    for (int m = 0; m < 4; ++m) {
        const int b = b0 + ty * 4 + m;
        float* orow = out + (long)b * NUM_COORDS + gbase;
        #pragma unroll
        for (int i2 = 0; i2 < 6; ++i2) {
            const int g = gbase + i2 * 2;
            if (g < NUM_COORDS) {
                float2 val;
                val.x = acc[m][2 * i2 + 0] + vtl[2 * i2 + 0];
                val.y = acc[m][2 * i2 + 1] + vtl[2 * i2 + 1];
                *(float2*)(orow + i2 * 2) = val;
            }
        }
    }
}

// ---------------- Kernel 3b: skinning, in-place on d_out ----------------
__global__ __launch_bounds__(256) void skin(float* __restrict__ out,
                                            const float* __restrict__ wT,
                                            const float* __restrict__ A) {
    const int b = blockIdx.y;
    const int v0 = blockIdx.x * 1024 + threadIdx.x * 4;   // 4 verts per thread
    if (v0 >= NUM_VERTS) return;
    const int gbase = v0 * 3;
    float* orow = out + (long)b * NUM_COORDS;

    float h[12];
    #pragma unroll
    for (int i2 = 0; i2 < 6; ++i2) {
        const int g = gbase + 2 * i2;
        if (g < NUM_COORDS) {
            const float2 t = *(const float2*)(orow + g);
            h[2 * i2] = t.x; h[2 * i2 + 1] = t.y;
        } else { h[2 * i2] = 0.f; h[2 * i2 + 1] = 0.f; }
    }

    float acc[12];
    #pragma unroll
    for (int i = 0; i < 12; ++i) acc[i] = 0.f;

    const float* Ab = A + b * 24 * 12;
    for (int j = 0; j < 24; ++j) {
        const float4 a0 = *(const float4*)(Ab + j * 12 + 0);
        const float4 a1 = *(const float4*)(Ab + j * 12 + 4);
        const float4 a2 = *(const float4*)(Ab + j * 12 + 8);
        const float4 w4 = *(const float4*)(wT + j * WT_STRIDE + v0);
        const float wm[4] = {w4.x, w4.y, w4.z, w4.w};
        #pragma unroll
        for (int m = 0; m < 4; ++m) {
            const float hx = h[m * 3 + 0], hy = h[m * 3 + 1], hz = h[m * 3 + 2];
            const float s0 = a0.x * hx + a0.y * hy + a0.z * hz + a0.w;
            const float s1 = a1.x * hx + a1.y * hy + a1.z * hz + a1.w;
            const float s2 = a2.x * hx + a2.y * hy + a2.z * hz + a2.w;
            acc[m * 3 + 0] += wm[m] * s0;
            acc[m * 3 + 1] += wm[m] * s1;
            acc[m * 3 + 2] += wm[m] * s2;
        }
    }

    #pragma unroll
    for (int i2 = 0; i2 < 6; ++i2) {
        const int g = gbase + 2 * i2;
        if (g < NUM_COORDS) {
            float2 val; val.x = acc[2 * i2]; val.y = acc[2 * i2 + 1];
            *(float2*)(orow + g) = val;
        }
    }
}

extern "C" void kernel_launch(void* const* d_in, const int* in_sizes, int n_in,
                              void* d_out, int out_size, void* d_ws, size_t ws_size,
                              hipStream_t stream) {
    const float* x  = (const float*)d_in[0];
    const float* vt = (const float*)d_in[1];
    const float* sd = (const float*)d_in[2];
    const float* Jr = (const float*)d_in[3];
    const float* pd = (const float*)d_in[4];
    const float* w  = (const float*)d_in[5];
    const int* parents = (const int*)d_in[6];
    float* out = (float*)d_out;
    float* ws  = (float*)d_ws;

    reduce_sj  <<<dim3(33, 24), 256, 0, stream>>>(Jr, sd, vt, ws);
    transpose_w<<<dim3(27, 24), 256, 0, stream>>>(w, ws + WS_WT);
    per_batch  <<<BATCH, 64, 0, stream>>>(x, parents, ws, ws + WS_A, ws + WS_XT);
    gemm_vposed<<<dim3(108, 8), 256, 0, stream>>>(sd, pd, vt, ws + WS_XT, out);
    skin       <<<dim3(7, BATCH), 256, 0, stream>>>(out, ws + WS_WT, ws + WS_A);
}

// Round 2
// 209.605 us; speedup vs baseline: 1.3163x; 1.3163x over previous
//
#include <hip/hip_runtime.h>

#define NUM_JOINTS 24
#define NUM_VERTS  6890
#define NUM_COORDS (NUM_VERTS * 3)   // 20670
#define NUM_BETAS  10
#define KTOT       217               // 10 betas + 207 pose features
#define KPAD       224               // padded K for MFMA (7 x 32)
#define BATCH      512
#define NPAD       20672             // 323 * 64 padded coord count

// ---- ws layout (float offsets) ----
#define WS_SJ 0
#define WS_JT 720
#define WS_A  800
#define WS_WT 259360
#define WT_STRIDE 6912
#define WS_XBF 425248   // ushort region: 512 x 224 bf16   (57344 floats)
#define WS_DBF 482592   // ushort region: 20672 x 224 bf16 (2315264 floats) -> ws total ~11.2 MB

typedef __attribute__((ext_vector_type(8))) short short8;
typedef __attribute__((ext_vector_type(4))) float f32x4;

__device__ inline unsigned short f2bf(float f) {
    union { float f; unsigned u; } c; c.f = f;
    unsigned u = c.u;
    u += 0x7fffu + ((u >> 16) & 1u);   // round-to-nearest-even
    return (unsigned short)(u >> 16);
}

// ---------------- Kernel 1: fold J_regressor into SJ / JT ----------------
__global__ __launch_bounds__(256) void reduce_sj(const float* __restrict__ Jr,
                                                 const float* __restrict__ sd,
                                                 const float* __restrict__ vt,
                                                 float* __restrict__ ws) {
    const int s = blockIdx.x;   // 0..32
    const int j = blockIdx.y;   // 0..23
    const int tid = threadIdx.x;
    float sum = 0.f;
    if (s < 30) {
        const int k = s / 3, c = s % 3;
        const float* src = sd + k * NUM_COORDS;
        for (int v = tid; v < NUM_VERTS; v += 256)
            sum += Jr[v * 24 + j] * src[v * 3 + c];
    } else {
        const int c = s - 30;
        for (int v = tid; v < NUM_VERTS; v += 256)
            sum += Jr[v * 24 + j] * vt[v * 3 + c];
    }
    __shared__ float red[256];
    red[tid] = sum;
    __syncthreads();
    for (int off = 128; off > 0; off >>= 1) {
        if (tid < off) red[tid] += red[tid + off];
        __syncthreads();
    }
    if (tid == 0) {
        if (s < 30) ws[WS_SJ + (s / 3) * 72 + j * 3 + (s % 3)] = red[0];
        else        ws[WS_JT + j * 3 + (s - 30)] = red[0];
    }
}

// ---------------- Kernel 1b: transpose lbs_weights -> wT[24][6912] ----------------
__global__ __launch_bounds__(256) void transpose_w(const float* __restrict__ w,
                                                   float* __restrict__ wT) {
    const int v = blockIdx.x * 256 + threadIdx.x;
    const int j = blockIdx.y;
    wT[j * WT_STRIDE + v] = (v < NUM_VERTS) ? w[v * 24 + j] : 0.f;
}

// ---------------- Kernel 1c: D (shapedirs|posedirs) -> DbfT[coord][k] bf16 ----------------
__global__ __launch_bounds__(256) void convert_dbf(const float* __restrict__ sd,
                                                   const float* __restrict__ pd,
                                                   unsigned short* __restrict__ dbf) {
    const int c = blockIdx.x * 256 + threadIdx.x;
    if (c >= NPAD) return;
    const bool valid = (c < NUM_COORDS);
    unsigned short* drow = dbf + (size_t)c * KPAD;
    for (int g = 0; g < 4; ++g) {
        unsigned buf[28];
        #pragma unroll
        for (int h = 0; h < 28; ++h) {
            const int k0 = g * 56 + 2 * h;
            const int k1 = k0 + 1;
            float v0 = 0.f, v1 = 0.f;
            if (valid) {
                v0 = (k0 < 10) ? sd[(size_t)k0 * NUM_COORDS + c]
                   : (k0 < KTOT) ? pd[(size_t)(k0 - 10) * NUM_COORDS + c] : 0.f;
                v1 = (k1 < 10) ? sd[(size_t)k1 * NUM_COORDS + c]
                   : (k1 < KTOT) ? pd[(size_t)(k1 - 10) * NUM_COORDS + c] : 0.f;
            }
            buf[h] = (unsigned)f2bf(v0) | ((unsigned)f2bf(v1) << 16);
        }
        #pragma unroll
        for (int h = 0; h < 7; ++h)
            *(float4*)(drow + g * 56 + h * 8) = *(const float4*)(&buf[h * 4]);
    }
}

// ---------------- Kernel 2: per-batch Rodrigues + joints + chain; emits A and Xbf ----------------
__global__ __launch_bounds__(64) void per_batch(const float* __restrict__ x,
                                                const int* __restrict__ parents,
                                                const float* __restrict__ ws_sj,
                                                float* __restrict__ ws_A,
                                                unsigned short* __restrict__ xbf) {
    const int b = blockIdx.x;
    const int tid = threadIdx.x;
    __shared__ float Rs[24][9], Jl[24][3], Rg[24][9], tg[24][3];
    const float* row = x + b * (NUM_BETAS + 72);

    if (tid < 24) {
        const int j = tid;
        const float t0 = row[3 * j + 0], t1 = row[3 * j + 1], t2 = row[3 * j + 2];
        const float a0 = t0 + 1e-8f, a1 = t1 + 1e-8f, a2 = t2 + 1e-8f;
        const float angle = sqrtf(a0 * a0 + a1 * a1 + a2 * a2);
        const float inv = 1.0f / angle;
        const float rx = t0 * inv, ry = t1 * inv, rz = t2 * inv;
        const float c = cosf(angle), sn = sinf(angle), o = 1.f - c;
        float R[9];
        R[0] = c + o * rx * rx;      R[1] = o * rx * ry - sn * rz; R[2] = o * rx * rz + sn * ry;
        R[3] = o * rx * ry + sn * rz; R[4] = c + o * ry * ry;      R[5] = o * ry * rz - sn * rx;
        R[6] = o * rx * rz - sn * ry; R[7] = o * ry * rz + sn * rx; R[8] = c + o * rz * rz;
        #pragma unroll
        for (int i = 0; i < 9; ++i) Rs[j][i] = R[i];
        #pragma unroll
        for (int c3 = 0; c3 < 3; ++c3) {
            float s = ws_sj[WS_JT + j * 3 + c3];
            #pragma unroll
            for (int k = 0; k < NUM_BETAS; ++k)
                s += row[72 + k] * ws_sj[WS_SJ + k * 72 + j * 3 + c3];
            Jl[j][c3] = s;
        }
        if (j >= 1) {
            #pragma unroll
            for (int i = 0; i < 9; ++i) {
                const float pf = R[i] - ((i == 0 || i == 4 || i == 8) ? 1.f : 0.f);
                xbf[(size_t)b * KPAD + 10 + (j - 1) * 9 + i] = f2bf(pf);
            }
        }
    }
    if (tid < NUM_BETAS) xbf[(size_t)b * KPAD + tid] = f2bf(row[72 + tid]);
    if (tid == 63) {
        #pragma unroll
        for (int k = KTOT; k < KPAD; ++k) xbf[(size_t)b * KPAD + k] = 0;
    }
    __syncthreads();

    if (tid == 0) {
        #pragma unroll
        for (int i = 0; i < 9; ++i) Rg[0][i] = Rs[0][i];
        #pragma unroll
        for (int c3 = 0; c3 < 3; ++c3) tg[0][c3] = Jl[0][c3];
        for (int i = 1; i < 24; ++i) {
            const int p = parents[i];
            float tmp[9];
            #pragma unroll
            for (int r = 0; r < 3; ++r)
                #pragma unroll
                for (int cc = 0; cc < 3; ++cc)
                    tmp[r * 3 + cc] = Rg[p][r * 3 + 0] * Rs[i][0 + cc] +
                                      Rg[p][r * 3 + 1] * Rs[i][3 + cc] +
                                      Rg[p][r * 3 + 2] * Rs[i][6 + cc];
            #pragma unroll
            for (int q = 0; q < 9; ++q) Rg[i][q] = tmp[q];
            const float tr0 = Jl[i][0] - Jl[p][0];
            const float tr1 = Jl[i][1] - Jl[p][1];
            const float tr2 = Jl[i][2] - Jl[p][2];
            #pragma unroll
            for (int r = 0; r < 3; ++r)
                tg[i][r] = Rg[p][r * 3 + 0] * tr0 + Rg[p][r * 3 + 1] * tr1 +
                           Rg[p][r * 3 + 2] * tr2 + tg[p][r];
        }
    }
    __syncthreads();

    if (tid < 24) {
        const int j = tid;
        float* Ab = ws_A + (b * 24 + j) * 12;
        #pragma unroll
        for (int r = 0; r < 3; ++r) {
            const float t = tg[j][r] - (Rg[j][r * 3 + 0] * Jl[j][0] +
                                        Rg[j][r * 3 + 1] * Jl[j][1] +
                                        Rg[j][r * 3 + 2] * Jl[j][2]);
            Ab[r * 4 + 0] = Rg[j][r * 3 + 0];
            Ab[r * 4 + 1] = Rg[j][r * 3 + 1];
            Ab[r * 4 + 2] = Rg[j][r * 3 + 2];
            Ab[r * 4 + 3] = t;
        }
    }
}

// ---------------- Kernel 3a: v_posed = X @ D + v_template via bf16 MFMA -> d_out ----------------
// Block: 64 coords (4 waves x 16), full M=512 in chunks of 64 batches.
// A-frag: Xs[m=lane&15][k=quad*8+j]; B-frag: DbfT[n=lane&15][k=quad*8+j];
// C: col(lane&15)=coord, row(quad*4+reg)=batch.
__global__ __launch_bounds__(256) void gemm_mfma(const unsigned short* __restrict__ dbf,
                                                 const unsigned short* __restrict__ xbf,
                                                 const float* __restrict__ vt,
                                                 float* __restrict__ out) {
    __shared__ __align__(16) unsigned short Xs[64 * 232];  // X chunk, row stride 232 (2-way banks)
    __shared__ float Cs[64 * 69];                          // C tile [coord][batch], stride 69
    const int tid  = threadIdx.x;
    const int wave = tid >> 6;
    const int lane = tid & 63;
    const int col  = lane & 15;
    const int quad = lane >> 4;
    const int n0   = blockIdx.x * 64;
    const int nc   = n0 + wave * 16 + col;   // this lane's coord column (< NPAD)

    short8 bfrag[7];
    {
        const unsigned short* brow = dbf + (size_t)nc * KPAD + quad * 8;
        #pragma unroll
        for (int kb = 0; kb < 7; ++kb)
            bfrag[kb] = *(const short8*)(brow + kb * 32);
    }
    const float vtl = (nc < NUM_COORDS) ? vt[nc] : 0.f;

    for (int m0 = 0; m0 < BATCH; m0 += 64) {
        __syncthreads();
        // stage X chunk: 64 rows x 448 B = 1792 16-B pieces = 256 threads x 7
        #pragma unroll
        for (int i = 0; i < 7; ++i) {
            const int c = tid + i * 256;
            const int row = c / 28;
            const int off = c % 28;
            const float4 v = *(const float4*)(xbf + (size_t)(m0 + row) * KPAD + off * 8);
            *(float4*)(&Xs[row * 232 + off * 8]) = v;
        }
        __syncthreads();

        #pragma unroll
        for (int mt = 0; mt < 4; ++mt) {
            const unsigned short* arow = &Xs[(mt * 16 + col) * 232 + quad * 8];
            f32x4 acc = {0.f, 0.f, 0.f, 0.f};
            #pragma unroll
            for (int kb = 0; kb < 7; ++kb) {
                const short8 afrag = *(const short8*)(arow + kb * 32);
                acc = __builtin_amdgcn_mfma_f32_16x16x32_bf16(afrag, bfrag[kb], acc, 0, 0, 0);
            }
            float* cdst = &Cs[(wave * 16 + col) * 69 + mt * 16 + quad * 4];
            cdst[0] = acc[0] + vtl;
            cdst[1] = acc[1] + vtl;
            cdst[2] = acc[2] + vtl;
            cdst[3] = acc[3] + vtl;
        }
        __syncthreads();
        // cooperative coalesced store: thread -> batch bl=tid>>2, coord quarter q=tid&3
        {
            const int bl = tid >> 2;
            const int q  = tid & 3;
            float* orow = out + (size_t)(m0 + bl) * NUM_COORDS + n0 + q * 16;
            #pragma unroll
            for (int i = 0; i < 8; ++i) {
                const int coord = n0 + q * 16 + 2 * i;
                if (coord < NUM_COORDS) {
                    float2 v;
                    v.x = Cs[(q * 16 + 2 * i)     * 69 + bl];
                    v.y = Cs[(q * 16 + 2 * i + 1) * 69 + bl];
                    *(float2*)(orow + 2 * i) = v;
                }
            }
        }
    }
}

// ---------------- Kernel 3b: skinning, in-place on d_out ----------------
__global__ __launch_bounds__(256) void skin(float* __restrict__ out,
                                            const float* __restrict__ wT,
                                            const float* __restrict__ A) {
    const int b = blockIdx.y;
    const int v0 = blockIdx.x * 1024 + threadIdx.x * 4;
    if (v0 >= NUM_VERTS) return;
    const int gbase = v0 * 3;
    float* orow = out + (size_t)b * NUM_COORDS;

    float h[12];
    #pragma unroll
    for (int i2 = 0; i2 < 6; ++i2) {
        const int g = gbase + 2 * i2;
        if (g < NUM_COORDS) {
            const float2 t = *(const float2*)(orow + g);
            h[2 * i2] = t.x; h[2 * i2 + 1] = t.y;
        } else { h[2 * i2] = 0.f; h[2 * i2 + 1] = 0.f; }
    }

    float acc[12];
    #pragma unroll
    for (int i = 0; i < 12; ++i) acc[i] = 0.f;

    const float* Ab = A + b * 24 * 12;
    for (int j = 0; j < 24; ++j) {
        const float4 a0 = *(const float4*)(Ab + j * 12 + 0);
        const float4 a1 = *(const float4*)(Ab + j * 12 + 4);
        const float4 a2 = *(const float4*)(Ab + j * 12 + 8);
        const float4 w4 = *(const float4*)(wT + j * WT_STRIDE + v0);
        const float wm[4] = {w4.x, w4.y, w4.z, w4.w};
        #pragma unroll
        for (int m = 0; m < 4; ++m) {
            const float hx = h[m * 3 + 0], hy = h[m * 3 + 1], hz = h[m * 3 + 2];
            acc[m * 3 + 0] += wm[m] * (a0.x * hx + a0.y * hy + a0.z * hz + a0.w);
            acc[m * 3 + 1] += wm[m] * (a1.x * hx + a1.y * hy + a1.z * hz + a1.w);
            acc[m * 3 + 2] += wm[m] * (a2.x * hx + a2.y * hy + a2.z * hz + a2.w);
        }
    }

    #pragma unroll
    for (int i2 = 0; i2 < 6; ++i2) {
        const int g = gbase + 2 * i2;
        if (g < NUM_COORDS) {
            float2 val; val.x = acc[2 * i2]; val.y = acc[2 * i2 + 1];
            *(float2*)(orow + g) = val;
        }
    }
}

extern "C" void kernel_launch(void* const* d_in, const int* in_sizes, int n_in,
                              void* d_out, int out_size, void* d_ws, size_t ws_size,
                              hipStream_t stream) {
    const float* x  = (const float*)d_in[0];
    const float* vt = (const float*)d_in[1];
    const float* sd = (const float*)d_in[2];
    const float* Jr = (const float*)d_in[3];
    const float* pd = (const float*)d_in[4];
    const float* w  = (const float*)d_in[5];
    const int* parents = (const int*)d_in[6];
    float* out = (float*)d_out;
    float* ws  = (float*)d_ws;
    unsigned short* xbf = (unsigned short*)(ws + WS_XBF);
    unsigned short* dbf = (unsigned short*)(ws + WS_DBF);

    reduce_sj  <<<dim3(33, 24), 256, 0, stream>>>(Jr, sd, vt, ws);
    transpose_w<<<dim3(27, 24), 256, 0, stream>>>(w, ws + WS_WT);
    per_batch  <<<BATCH, 64, 0, stream>>>(x, parents, ws, ws + WS_A, xbf);
    convert_dbf<<<81, 256, 0, stream>>>(sd, pd, dbf);
    gemm_mfma  <<<323, 256, 0, stream>>>(dbf, xbf, vt, out);
    skin       <<<dim3(7, BATCH), 256, 0, stream>>>(out, ws + WS_WT, ws + WS_A);
}

// Round 3
// 165.649 us; speedup vs baseline: 1.6655x; 1.2654x over previous
//
#include <hip/hip_runtime.h>

#define NUM_JOINTS 24
#define NUM_VERTS  6890
#define NUM_COORDS (NUM_VERTS * 3)   // 20670
#define NUM_BETAS  10
#define KTOT       217               // 10 betas + 207 pose features
#define KPAD       224               // padded K for MFMA (7 x 32)
#define BATCH      512
#define NPAD       20672             // 323 * 64 padded coord count
#define VPAD       6912              // padded vertex count

// ---- ws layout (float offsets) ----
#define WS_SJ   0          //  720: SJ[k][j][c]
#define WS_JT   720        //   72: JT[j][c]
#define WS_XBF  800        //  57344: ushort 512 x 224 bf16 (X rows)
#define WS_DBF  58144      // 2315264: ushort 20672 x 224 bf16 (D^T rows)
#define WS_WHBF 2373408    // 110592: ushort 6912 x 32 bf16 (W rows, joint-padded)
#define WS_AH   2484000    // 131072: ushort 8192 x 32 bf16 (A' hi rows: (b*16+pq) x k)
#define WS_AL   2615072    // 131072: ushort 8192 x 32 bf16 (A' lo)
#define WS_JRT  2746144    // 165888: float 24 x 6912 (Jr transposed)

typedef __attribute__((ext_vector_type(8))) short short8;
typedef __attribute__((ext_vector_type(4))) float f32x4;

__device__ inline unsigned short f2bf(float f) {
    union { float f; unsigned u; } c; c.f = f;
    unsigned u = c.u;
    u += 0x7fffu + ((u >> 16) & 1u);   // RNE
    return (unsigned short)(u >> 16);
}
__device__ inline float bf2f(unsigned short h) {
    union { unsigned u; float f; } c; c.u = ((unsigned)h) << 16;
    return c.f;
}

// ---------------- transpose Jr -> JrT[24][6912] ----------------
__global__ __launch_bounds__(256) void transpose_jr(const float* __restrict__ Jr,
                                                    float* __restrict__ jrT) {
    const int v = blockIdx.x * 256 + threadIdx.x;
    if (v >= VPAD) return;
    #pragma unroll
    for (int j = 0; j < 24; ++j)
        jrT[j * VPAD + v] = (v < NUM_VERTS) ? Jr[v * 24 + j] : 0.f;
}

// ---------------- fold J_regressor into SJ / JT (coalesced via JrT) ----------------
__global__ __launch_bounds__(256) void reduce_sj(const float* __restrict__ jrT,
                                                 const float* __restrict__ sd,
                                                 const float* __restrict__ vt,
                                                 float* __restrict__ ws) {
    const int s = blockIdx.x;   // 0..32
    const int j = blockIdx.y;   // 0..23
    const int tid = threadIdx.x;
    const float* jr = jrT + j * VPAD;
    float sum = 0.f;
    if (s < 30) {
        const int k = s / 3, c = s % 3;
        const float* src = sd + (size_t)k * NUM_COORDS;
        for (int v = tid; v < NUM_VERTS; v += 256)
            sum += jr[v] * src[v * 3 + c];
    } else {
        const int c = s - 30;
        for (int v = tid; v < NUM_VERTS; v += 256)
            sum += jr[v] * vt[v * 3 + c];
    }
    __shared__ float red[256];
    red[tid] = sum;
    __syncthreads();
    for (int off = 128; off > 0; off >>= 1) {
        if (tid < off) red[tid] += red[tid + off];
        __syncthreads();
    }
    if (tid == 0) {
        if (s < 30) ws[WS_SJ + (s / 3) * 72 + j * 3 + (s % 3)] = red[0];
        else        ws[WS_JT + j * 3 + (s - 30)] = red[0];
    }
}

// ---------------- lbs_weights -> Whbf[vert][32] bf16 (A-operand rows) ----------------
__global__ __launch_bounds__(256) void make_whbf(const float* __restrict__ w,
                                                 unsigned short* __restrict__ whbf) {
    const int v = blockIdx.x * 256 + threadIdx.x;
    if (v >= VPAD) return;
    unsigned short row[32];
    #pragma unroll
    for (int j = 0; j < 32; ++j) {
        const float val = (v < NUM_VERTS && j < 24) ? w[v * 24 + j] : 0.f;
        row[j] = f2bf(val);
    }
    #pragma unroll
    for (int i = 0; i < 4; ++i)
        *(float4*)(whbf + (size_t)v * 32 + i * 8) = *(const float4*)(&row[i * 8]);
}

// ---------------- D (shapedirs|posedirs) -> DbfT[coord][k] bf16 ----------------
__global__ __launch_bounds__(256) void convert_dbf(const float* __restrict__ sd,
                                                   const float* __restrict__ pd,
                                                   unsigned short* __restrict__ dbf) {
    const int c = blockIdx.x * 256 + threadIdx.x;
    if (c >= NPAD) return;
    const bool valid = (c < NUM_COORDS);
    unsigned short* drow = dbf + (size_t)c * KPAD;
    for (int g = 0; g < 4; ++g) {
        unsigned buf[28];
        #pragma unroll
        for (int h = 0; h < 28; ++h) {
            const int k0 = g * 56 + 2 * h;
            const int k1 = k0 + 1;
            float v0 = 0.f, v1 = 0.f;
            if (valid) {
                v0 = (k0 < 10) ? sd[(size_t)k0 * NUM_COORDS + c]
                   : (k0 < KTOT) ? pd[(size_t)(k0 - 10) * NUM_COORDS + c] : 0.f;
                v1 = (k1 < 10) ? sd[(size_t)k1 * NUM_COORDS + c]
                   : (k1 < KTOT) ? pd[(size_t)(k1 - 10) * NUM_COORDS + c] : 0.f;
            }
            buf[h] = (unsigned)f2bf(v0) | ((unsigned)f2bf(v1) << 16);
        }
        #pragma unroll
        for (int h = 0; h < 7; ++h)
            *(float4*)(drow + g * 56 + h * 8) = *(const float4*)(&buf[h * 4]);
    }
}

// ---------------- per-batch: Rodrigues + joints + chain; emits Xbf and A' hi/lo ----------------
__global__ __launch_bounds__(64) void per_batch(const float* __restrict__ x,
                                                const int* __restrict__ parents,
                                                const float* __restrict__ ws_sj,
                                                unsigned short* __restrict__ ahi,
                                                unsigned short* __restrict__ alo,
                                                unsigned short* __restrict__ xbf) {
    const int b = blockIdx.x;
    const int tid = threadIdx.x;
    __shared__ float Rs[24][9], Jl[24][3], Rg[24][9], tg[24][3], As[24][12];
    const float* row = x + b * (NUM_BETAS + 72);

    if (tid < 24) {
        const int j = tid;
        const float t0 = row[3 * j + 0], t1 = row[3 * j + 1], t2 = row[3 * j + 2];
        const float a0 = t0 + 1e-8f, a1 = t1 + 1e-8f, a2 = t2 + 1e-8f;
        const float angle = sqrtf(a0 * a0 + a1 * a1 + a2 * a2);
        const float inv = 1.0f / angle;
        const float rx = t0 * inv, ry = t1 * inv, rz = t2 * inv;
        const float c = cosf(angle), sn = sinf(angle), o = 1.f - c;
        float R[9];
        R[0] = c + o * rx * rx;       R[1] = o * rx * ry - sn * rz; R[2] = o * rx * rz + sn * ry;
        R[3] = o * rx * ry + sn * rz; R[4] = c + o * ry * ry;       R[5] = o * ry * rz - sn * rx;
        R[6] = o * rx * rz - sn * ry; R[7] = o * ry * rz + sn * rx; R[8] = c + o * rz * rz;
        #pragma unroll
        for (int i = 0; i < 9; ++i) Rs[j][i] = R[i];
        #pragma unroll
        for (int c3 = 0; c3 < 3; ++c3) {
            float s = ws_sj[WS_JT + j * 3 + c3];
            #pragma unroll
            for (int k = 0; k < NUM_BETAS; ++k)
                s += row[72 + k] * ws_sj[WS_SJ + k * 72 + j * 3 + c3];
            Jl[j][c3] = s;
        }
        if (j >= 1) {
            #pragma unroll
            for (int i = 0; i < 9; ++i) {
                const float pf = R[i] - ((i == 0 || i == 4 || i == 8) ? 1.f : 0.f);
                xbf[(size_t)b * KPAD + 10 + (j - 1) * 9 + i] = f2bf(pf);
            }
        }
    }
    if (tid < NUM_BETAS) xbf[(size_t)b * KPAD + tid] = f2bf(row[72 + tid]);
    if (tid == 63) {
        #pragma unroll
        for (int k = KTOT; k < KPAD; ++k) xbf[(size_t)b * KPAD + k] = 0;
    }
    __syncthreads();

    if (tid == 0) {
        #pragma unroll
        for (int i = 0; i < 9; ++i) Rg[0][i] = Rs[0][i];
        #pragma unroll
        for (int c3 = 0; c3 < 3; ++c3) tg[0][c3] = Jl[0][c3];
        for (int i = 1; i < 24; ++i) {
            const int p = parents[i];
            float tmp[9];
            #pragma unroll
            for (int r = 0; r < 3; ++r)
                #pragma unroll
                for (int cc = 0; cc < 3; ++cc)
                    tmp[r * 3 + cc] = Rg[p][r * 3 + 0] * Rs[i][0 + cc] +
                                      Rg[p][r * 3 + 1] * Rs[i][3 + cc] +
                                      Rg[p][r * 3 + 2] * Rs[i][6 + cc];
            #pragma unroll
            for (int q = 0; q < 9; ++q) Rg[i][q] = tmp[q];
            const float tr0 = Jl[i][0] - Jl[p][0];
            const float tr1 = Jl[i][1] - Jl[p][1];
            const float tr2 = Jl[i][2] - Jl[p][2];
            #pragma unroll
            for (int r = 0; r < 3; ++r)
                tg[i][r] = Rg[p][r * 3 + 0] * tr0 + Rg[p][r * 3 + 1] * tr1 +
                           Rg[p][r * 3 + 2] * tr2 + tg[p][r];
        }
    }
    __syncthreads();

    if (tid < 24) {
        const int j = tid;
        #pragma unroll
        for (int r = 0; r < 3; ++r) {
            const float t = tg[j][r] - (Rg[j][r * 3 + 0] * Jl[j][0] +
                                        Rg[j][r * 3 + 1] * Jl[j][1] +
                                        Rg[j][r * 3 + 2] * Jl[j][2]);
            As[j][r * 4 + 0] = Rg[j][r * 3 + 0];
            As[j][r * 4 + 1] = Rg[j][r * 3 + 1];
            As[j][r * 4 + 2] = Rg[j][r * 3 + 2];
            As[j][r * 4 + 3] = t;
        }
    }
    __syncthreads();

    // Emit A' hi/lo rows: row (b*16 + pq), 32 k-entries (joints padded to 32)
    if (tid < 32) {
        const int r = tid >> 1;      // pq row 0..15
        const int half = tid & 1;    // k half: 0..15 / 16..31
        unsigned short hi[16], lo[16];
        #pragma unroll
        for (int i = 0; i < 16; ++i) {
            const int j = half * 16 + i;
            float v = 0.f;
            if (r < 12 && j < 24) v = As[j][r];
            const unsigned short h = f2bf(v);
            hi[i] = h;
            lo[i] = f2bf(v - bf2f(h));
        }
        unsigned short* dh = ahi + ((size_t)b * 16 + r) * 32 + half * 16;
        unsigned short* dl = alo + ((size_t)b * 16 + r) * 32 + half * 16;
        #pragma unroll
        for (int i = 0; i < 2; ++i) {
            *(float4*)(dh + i * 8) = *(const float4*)(&hi[i * 8]);
            *(float4*)(dl + i * 8) = *(const float4*)(&lo[i * 8]);
        }
    }
}

// ---------------- GEMM1: v_posed = X @ D + v_template (MFMA, direct stores) ----------------
// grid (323, 4): 64-coord strip x 128-batch split (2 chunks of 64).
__global__ __launch_bounds__(256) void gemm_mfma(const unsigned short* __restrict__ dbf,
                                                 const unsigned short* __restrict__ xbf,
                                                 const float* __restrict__ vt,
                                                 float* __restrict__ out) {
    __shared__ __align__(16) unsigned short Xs[64 * 232];
    const int tid  = threadIdx.x;
    const int wave = tid >> 6;
    const int lane = tid & 63;
    const int col  = lane & 15;
    const int quad = lane >> 4;
    const int n0   = blockIdx.x * 64;
    const int nc   = n0 + wave * 16 + col;

    short8 bfrag[7];
    {
        const unsigned short* brow = dbf + (size_t)nc * KPAD + quad * 8;
        #pragma unroll
        for (int kb = 0; kb < 7; ++kb)
            bfrag[kb] = *(const short8*)(brow + kb * 32);
    }
    const float vtl = (nc < NUM_COORDS) ? vt[nc] : 0.f;
    const bool nok = (nc < NUM_COORDS);

    for (int chunk = 0; chunk < 2; ++chunk) {
        const int m0 = blockIdx.y * 128 + chunk * 64;
        __syncthreads();
        #pragma unroll
        for (int i = 0; i < 7; ++i) {
            const int c = tid + i * 256;
            const int r = c / 28;
            const int off = c % 28;
            const float4 v = *(const float4*)(xbf + (size_t)(m0 + r) * KPAD + off * 8);
            *(float4*)(&Xs[r * 232 + off * 8]) = v;
        }
        __syncthreads();

        #pragma unroll
        for (int mt = 0; mt < 4; ++mt) {
            const unsigned short* arow = &Xs[(mt * 16 + col) * 232 + quad * 8];
            f32x4 acc = {0.f, 0.f, 0.f, 0.f};
            #pragma unroll
            for (int kb = 0; kb < 7; ++kb) {
                const short8 afrag = *(const short8*)(arow + kb * 32);
                acc = __builtin_amdgcn_mfma_f32_16x16x32_bf16(afrag, bfrag[kb], acc, 0, 0, 0);
            }
            if (nok) {
                float* base = out + (size_t)(m0 + mt * 16 + quad * 4) * NUM_COORDS + nc;
                base[0]                       = acc[0] + vtl;
                base[(size_t)NUM_COORDS]      = acc[1] + vtl;
                base[(size_t)2 * NUM_COORDS]  = acc[2] + vtl;
                base[(size_t)3 * NUM_COORDS]  = acc[3] + vtl;
            }
        }
    }
}

// ---------------- GEMM2 (skin): T = W @ A' (bf16 hi/lo), apply T*h in-place on d_out ----------------
// grid (108, 16): 64-vert tile x 32-batch split; wave handles 8 batches (n-tiles).
__global__ __launch_bounds__(256) void skin_mfma(const unsigned short* __restrict__ whbf,
                                                 const unsigned short* __restrict__ ahi,
                                                 const unsigned short* __restrict__ alo,
                                                 float* __restrict__ out) {
    __shared__ float Ts[4][64 * 17];
    const int tid  = threadIdx.x;
    const int wave = tid >> 6;
    const int lane = tid & 63;
    const int col  = lane & 15;
    const int quad = lane >> 4;
    const int v0   = blockIdx.x * 64;
    const int b0   = blockIdx.y * 32;

    short8 wfrag[4];
    #pragma unroll
    for (int mt = 0; mt < 4; ++mt)
        wfrag[mt] = *(const short8*)(whbf + (size_t)(v0 + mt * 16 + col) * 32 + quad * 8);

    float* ts = &Ts[wave][0];
    const int vv = v0 + lane;
    const bool vok = (vv < NUM_VERTS);

    for (int nt = wave; nt < 32; nt += 4) {
        const int b = b0 + nt;
        float* orow = out + (size_t)b * NUM_COORDS + (size_t)vv * 3;
        float h0 = 0.f, h1 = 0.f, h2 = 0.f;
        if (vok) { h0 = orow[0]; h1 = orow[1]; h2 = orow[2]; }

        const short8 bh = *(const short8*)(ahi + ((size_t)b * 16 + col) * 32 + quad * 8);
        const short8 bl = *(const short8*)(alo + ((size_t)b * 16 + col) * 32 + quad * 8);

        f32x4 acc[4];
        #pragma unroll
        for (int mt = 0; mt < 4; ++mt) {
            f32x4 z = {0.f, 0.f, 0.f, 0.f};
            z = __builtin_amdgcn_mfma_f32_16x16x32_bf16(wfrag[mt], bh, z, 0, 0, 0);
            z = __builtin_amdgcn_mfma_f32_16x16x32_bf16(wfrag[mt], bl, z, 0, 0, 0);
            acc[mt] = z;
        }
        // per-wave LDS transpose: rows = local vert, cols = pq
        #pragma unroll
        for (int mt = 0; mt < 4; ++mt)
            #pragma unroll
            for (int r = 0; r < 4; ++r)
                ts[(mt * 16 + quad * 4 + r) * 17 + col] = acc[mt][r];

        float Tp[12];
        #pragma unroll
        for (int i = 0; i < 12; ++i) Tp[i] = ts[lane * 17 + i];

        if (vok) {
            const float o0 = Tp[0] * h0 + Tp[1] * h1 + Tp[2]  * h2 + Tp[3];
            const float o1 = Tp[4] * h0 + Tp[5] * h1 + Tp[6]  * h2 + Tp[7];
            const float o2 = Tp[8] * h0 + Tp[9] * h1 + Tp[10] * h2 + Tp[11];
            orow[0] = o0; orow[1] = o1; orow[2] = o2;
        }
    }
}

extern "C" void kernel_launch(void* const* d_in, const int* in_sizes, int n_in,
                              void* d_out, int out_size, void* d_ws, size_t ws_size,
                              hipStream_t stream) {
    const float* x  = (const float*)d_in[0];
    const float* vt = (const float*)d_in[1];
    const float* sd = (const float*)d_in[2];
    const float* Jr = (const float*)d_in[3];
    const float* pd = (const float*)d_in[4];
    const float* w  = (const float*)d_in[5];
    const int* parents = (const int*)d_in[6];
    float* out = (float*)d_out;
    float* ws  = (float*)d_ws;
    unsigned short* xbf  = (unsigned short*)(ws + WS_XBF);
    unsigned short* dbf  = (unsigned short*)(ws + WS_DBF);
    unsigned short* whbf = (unsigned short*)(ws + WS_WHBF);
    unsigned short* ahi  = (unsigned short*)(ws + WS_AH);
    unsigned short* alo  = (unsigned short*)(ws + WS_AL);
    float* jrT = ws + WS_JRT;

    transpose_jr<<<27, 256, 0, stream>>>(Jr, jrT);
    reduce_sj   <<<dim3(33, 24), 256, 0, stream>>>(jrT, sd, vt, ws);
    make_whbf   <<<27, 256, 0, stream>>>(w, whbf);
    convert_dbf <<<81, 256, 0, stream>>>(sd, pd, dbf);
    per_batch   <<<BATCH, 64, 0, stream>>>(x, parents, ws, ahi, alo, xbf);
    gemm_mfma   <<<dim3(323, 4), 256, 0, stream>>>(dbf, xbf, vt, out);
    skin_mfma   <<<dim3(108, 16), 256, 0, stream>>>(whbf, ahi, alo, out);
}

// Round 7
// 165.596 us; speedup vs baseline: 1.6661x; 1.0003x over previous
//
#include <hip/hip_runtime.h>

#define NUM_JOINTS 24
#define NUM_VERTS  6890
#define NUM_COORDS (NUM_VERTS * 3)   // 20670
#define NUM_BETAS  10
#define KTOT       217               // 10 betas + 207 pose features
#define KPAD       224               // padded K for MFMA (7 x 32)
#define BATCH      512
#define NPAD       20672             // 323 * 64 gemm grid coverage
#define DPAD       20736             // 81 * 256 dbf rows allocated/written
#define VPAD       6912              // padded vertex count

// ---- ws layout (float offsets); ushort regions: floats = ushorts/2 ----
#define WS_SJ   0          //    720: SJ[k][j][c]
#define WS_JT   720        //     72: JT[j][c]                      (pad to 800)
#define WS_XBF  800        //  57344: ushort 512 x 224   (114688 us)
#define WS_DBF  58144      // 2322432: ushort 20736 x 224
#define WS_WHBF 2380576    // 110592: ushort 6912 x 32
#define WS_AH   2491168    // 131072: ushort 8192 x 32
#define WS_AL   2622240    // 131072: ushort 8192 x 32
#define WS_JRT  2753312    // 165888: float 24 x 6912  -> total 2919200 floats ~ 11.7 MB

typedef __attribute__((ext_vector_type(8))) short short8;
typedef __attribute__((ext_vector_type(4))) float f32x4;

__device__ inline unsigned short f2bf(float f) {
    union { float f; unsigned u; } c; c.f = f;
    unsigned u = c.u;
    u += 0x7fffu + ((u >> 16) & 1u);   // RNE
    return (unsigned short)(u >> 16);
}
__device__ inline float bf2f(unsigned short h) {
    union { unsigned u; float f; } c; c.u = ((unsigned)h) << 16;
    return c.f;
}

// ---------------- prep_vert: JrT[24][6912] + Whbf[6912][32] ----------------
__global__ __launch_bounds__(256) void prep_vert(const float* __restrict__ Jr,
                                                 const float* __restrict__ w,
                                                 float* __restrict__ jrT,
                                                 unsigned short* __restrict__ whbf) {
    const int v = blockIdx.x * 256 + threadIdx.x;
    if (v >= VPAD) return;
    const bool ok = (v < NUM_VERTS);
    #pragma unroll
    for (int j = 0; j < 24; ++j)
        jrT[j * VPAD + v] = ok ? Jr[v * 24 + j] : 0.f;
    unsigned short row[32];
    #pragma unroll
    for (int j = 0; j < 32; ++j)
        row[j] = f2bf((ok && j < 24) ? w[v * 24 + j] : 0.f);
    #pragma unroll
    for (int i = 0; i < 4; ++i)
        *(float4*)(whbf + (size_t)v * 32 + i * 8) = *(const float4*)(&row[i * 8]);
}

// ---------------- fold J_regressor into SJ / JT ----------------
__global__ __launch_bounds__(256) void reduce_sj(const float* __restrict__ jrT,
                                                 const float* __restrict__ sd,
                                                 const float* __restrict__ vt,
                                                 float* __restrict__ ws) {
    const int s = blockIdx.x;   // 0..32
    const int j = blockIdx.y;   // 0..23
    const int tid = threadIdx.x;
    const float* jr = jrT + j * VPAD;
    float sum = 0.f;
    if (s < 30) {
        const int k = s / 3, c = s % 3;
        const float* src = sd + (size_t)k * NUM_COORDS;
        for (int v = tid; v < NUM_VERTS; v += 256)
            sum += jr[v] * src[v * 3 + c];
    } else {
        const int c = s - 30;
        for (int v = tid; v < NUM_VERTS; v += 256)
            sum += jr[v] * vt[v * 3 + c];
    }
    __shared__ float red[256];
    red[tid] = sum;
    __syncthreads();
    for (int off = 128; off > 0; off >>= 1) {
        if (tid < off) red[tid] += red[tid + off];
        __syncthreads();
    }
    if (tid == 0) {
        if (s < 30) ws[WS_SJ + (s / 3) * 72 + j * 3 + (s % 3)] = red[0];
        else        ws[WS_JT + j * 3 + (s - 30)] = red[0];
    }
}

// ---------------- D (shapedirs|posedirs) -> DbfT[coord][k] bf16 ----------------
__global__ __launch_bounds__(256) void convert_dbf(const float* __restrict__ sd,
                                                   const float* __restrict__ pd,
                                                   unsigned short* __restrict__ dbf) {
    const int c = blockIdx.x * 256 + threadIdx.x;   // < 20736 exactly (81*256)
    const bool valid = (c < NUM_COORDS);
    unsigned short* drow = dbf + (size_t)c * KPAD;
    for (int g = 0; g < 4; ++g) {
        unsigned buf[28];
        #pragma unroll
        for (int h = 0; h < 28; ++h) {
            const int k0 = g * 56 + 2 * h;
            const int k1 = k0 + 1;
            float v0 = 0.f, v1 = 0.f;
            if (valid) {
                v0 = (k0 < 10) ? sd[(size_t)k0 * NUM_COORDS + c]
                   : (k0 < KTOT) ? pd[(size_t)(k0 - 10) * NUM_COORDS + c] : 0.f;
                v1 = (k1 < 10) ? sd[(size_t)k1 * NUM_COORDS + c]
                   : (k1 < KTOT) ? pd[(size_t)(k1 - 10) * NUM_COORDS + c] : 0.f;
            }
            buf[h] = (unsigned)f2bf(v0) | ((unsigned)f2bf(v1) << 16);
        }
        #pragma unroll
        for (int h = 0; h < 7; ++h)
            *(float4*)(drow + g * 56 + h * 8) = *(const float4*)(&buf[h * 4]);
    }
}

// ---------------- per-batch: Rodrigues + joints + chain; emits Xbf and A' hi/lo ----------------
__global__ __launch_bounds__(64) void per_batch(const float* __restrict__ x,
                                                const int* __restrict__ parents,
                                                const float* __restrict__ ws_sj,
                                                unsigned short* __restrict__ ahi,
                                                unsigned short* __restrict__ alo,
                                                unsigned short* __restrict__ xbf) {
    const int b = blockIdx.x;
    const int tid = threadIdx.x;
    __shared__ float Rs[24][9], Jl[24][3], Rg[24][9], tg[24][3], As[24][12];
    const float* row = x + b * (NUM_BETAS + 72);

    if (tid < 24) {
        const int j = tid;
        const float t0 = row[3 * j + 0], t1 = row[3 * j + 1], t2 = row[3 * j + 2];
        const float a0 = t0 + 1e-8f, a1 = t1 + 1e-8f, a2 = t2 + 1e-8f;
        const float angle = sqrtf(a0 * a0 + a1 * a1 + a2 * a2);
        const float inv = 1.0f / angle;
        const float rx = t0 * inv, ry = t1 * inv, rz = t2 * inv;
        const float c = cosf(angle), sn = sinf(angle), o = 1.f - c;
        float R[9];
        R[0] = c + o * rx * rx;       R[1] = o * rx * ry - sn * rz; R[2] = o * rx * rz + sn * ry;
        R[3] = o * rx * ry + sn * rz; R[4] = c + o * ry * ry;       R[5] = o * ry * rz - sn * rx;
        R[6] = o * rx * rz - sn * ry; R[7] = o * ry * rz + sn * rx; R[8] = c + o * rz * rz;
        #pragma unroll
        for (int i = 0; i < 9; ++i) Rs[j][i] = R[i];
        #pragma unroll
        for (int c3 = 0; c3 < 3; ++c3) {
            float s = ws_sj[WS_JT + j * 3 + c3];
            #pragma unroll
            for (int k = 0; k < NUM_BETAS; ++k)
                s += row[72 + k] * ws_sj[WS_SJ + k * 72 + j * 3 + c3];
            Jl[j][c3] = s;
        }
        if (j >= 1) {
            #pragma unroll
            for (int i = 0; i < 9; ++i) {
                const float pf = R[i] - ((i == 0 || i == 4 || i == 8) ? 1.f : 0.f);
                xbf[(size_t)b * KPAD + 10 + (j - 1) * 9 + i] = f2bf(pf);
            }
        }
    }
    if (tid < NUM_BETAS) xbf[(size_t)b * KPAD + tid] = f2bf(row[72 + tid]);
    if (tid == 63) {
        #pragma unroll
        for (int k = KTOT; k < KPAD; ++k) xbf[(size_t)b * KPAD + k] = 0;
    }
    __syncthreads();

    if (tid == 0) {
        #pragma unroll
        for (int i = 0; i < 9; ++i) Rg[0][i] = Rs[0][i];
        #pragma unroll
        for (int c3 = 0; c3 < 3; ++c3) tg[0][c3] = Jl[0][c3];
        for (int i = 1; i < 24; ++i) {
            const int p = parents[i];
            float tmp[9];
            #pragma unroll
            for (int r = 0; r < 3; ++r)
                #pragma unroll
                for (int cc = 0; cc < 3; ++cc)
                    tmp[r * 3 + cc] = Rg[p][r * 3 + 0] * Rs[i][0 + cc] +
                                      Rg[p][r * 3 + 1] * Rs[i][3 + cc] +
                                      Rg[p][r * 3 + 2] * Rs[i][6 + cc];
            #pragma unroll
            for (int q = 0; q < 9; ++q) Rg[i][q] = tmp[q];
            const float tr0 = Jl[i][0] - Jl[p][0];
            const float tr1 = Jl[i][1] - Jl[p][1];
            const float tr2 = Jl[i][2] - Jl[p][2];
            #pragma unroll
            for (int r = 0; r < 3; ++r)
                tg[i][r] = Rg[p][r * 3 + 0] * tr0 + Rg[p][r * 3 + 1] * tr1 +
                           Rg[p][r * 3 + 2] * tr2 + tg[p][r];
        }
    }
    __syncthreads();

    if (tid < 24) {
        const int j = tid;
        #pragma unroll
        for (int r = 0; r < 3; ++r) {
            const float t = tg[j][r] - (Rg[j][r * 3 + 0] * Jl[j][0] +
                                        Rg[j][r * 3 + 1] * Jl[j][1] +
                                        Rg[j][r * 3 + 2] * Jl[j][2]);
            As[j][r * 4 + 0] = Rg[j][r * 3 + 0];
            As[j][r * 4 + 1] = Rg[j][r * 3 + 1];
            As[j][r * 4 + 2] = Rg[j][r * 3 + 2];
            As[j][r * 4 + 3] = t;
        }
    }
    __syncthreads();

    if (tid < 32) {
        const int r = tid >> 1;      // pq row 0..15
        const int half = tid & 1;    // k half
        unsigned short hi[16], lo[16];
        #pragma unroll
        for (int i = 0; i < 16; ++i) {
            const int j = half * 16 + i;
            float v = 0.f;
            if (r < 12 && j < 24) v = As[j][r];
            const unsigned short h = f2bf(v);
            hi[i] = h;
            lo[i] = f2bf(v - bf2f(h));
        }
        unsigned short* dh = ahi + ((size_t)b * 16 + r) * 32 + half * 16;
        unsigned short* dl = alo + ((size_t)b * 16 + r) * 32 + half * 16;
        #pragma unroll
        for (int i = 0; i < 2; ++i) {
            *(float4*)(dh + i * 8) = *(const float4*)(&hi[i * 8]);
            *(float4*)(dl + i * 8) = *(const float4*)(&lo[i * 8]);
        }
    }
}

// ---------------- GEMM1 (ROUND-3 VERBATIM): v_posed = X @ D + v_template ----------------
// grid (323, 4): 64-coord strip x 128-batch split (2 chunks of 64).
__global__ __launch_bounds__(256) void gemm_mfma(const unsigned short* __restrict__ dbf,
                                                 const unsigned short* __restrict__ xbf,
                                                 const float* __restrict__ vt,
                                                 float* __restrict__ out) {
    __shared__ __align__(16) unsigned short Xs[64 * 232];
    const int tid  = threadIdx.x;
    const int wave = tid >> 6;
    const int lane = tid & 63;
    const int col  = lane & 15;
    const int quad = lane >> 4;
    const int n0   = blockIdx.x * 64;
    const int nc   = n0 + wave * 16 + col;

    short8 bfrag[7];
    {
        const unsigned short* brow = dbf + (size_t)nc * KPAD + quad * 8;
        #pragma unroll
        for (int kb = 0; kb < 7; ++kb)
            bfrag[kb] = *(const short8*)(brow + kb * 32);
    }
    const float vtl = (nc < NUM_COORDS) ? vt[nc] : 0.f;
    const bool nok = (nc < NUM_COORDS);

    for (int chunk = 0; chunk < 2; ++chunk) {
        const int m0 = blockIdx.y * 128 + chunk * 64;
        __syncthreads();
        #pragma unroll
        for (int i = 0; i < 7; ++i) {
            const int c = tid + i * 256;
            const int r = c / 28;
            const int off = c % 28;
            const float4 v = *(const float4*)(xbf + (size_t)(m0 + r) * KPAD + off * 8);
            *(float4*)(&Xs[r * 232 + off * 8]) = v;
        }
        __syncthreads();

        #pragma unroll
        for (int mt = 0; mt < 4; ++mt) {
            const unsigned short* arow = &Xs[(mt * 16 + col) * 232 + quad * 8];
            f32x4 acc = {0.f, 0.f, 0.f, 0.f};
            #pragma unroll
            for (int kb = 0; kb < 7; ++kb) {
                const short8 afrag = *(const short8*)(arow + kb * 32);
                acc = __builtin_amdgcn_mfma_f32_16x16x32_bf16(afrag, bfrag[kb], acc, 0, 0, 0);
            }
            if (nok) {
                float* base = out + (size_t)(m0 + mt * 16 + quad * 4) * NUM_COORDS + nc;
                base[0]                       = acc[0] + vtl;
                base[(size_t)NUM_COORDS]      = acc[1] + vtl;
                base[(size_t)2 * NUM_COORDS]  = acc[2] + vtl;
                base[(size_t)3 * NUM_COORDS]  = acc[3] + vtl;
            }
        }
    }
}

// ---------------- GEMM2 (ROUND-3 VERBATIM skin): T = W @ A' (bf16 hi/lo), in-place ----------------
// grid (108, 16): 64-vert tile x 32-batch split; wave handles 8 batches (n-tiles).
__global__ __launch_bounds__(256) void skin_mfma(const unsigned short* __restrict__ whbf,
                                                 const unsigned short* __restrict__ ahi,
                                                 const unsigned short* __restrict__ alo,
                                                 float* __restrict__ out) {
    __shared__ float Ts[4][64 * 17];
    const int tid  = threadIdx.x;
    const int wave = tid >> 6;
    const int lane = tid & 63;
    const int col  = lane & 15;
    const int quad = lane >> 4;
    const int v0   = blockIdx.x * 64;
    const int b0   = blockIdx.y * 32;

    short8 wfrag[4];
    #pragma unroll
    for (int mt = 0; mt < 4; ++mt)
        wfrag[mt] = *(const short8*)(whbf + (size_t)(v0 + mt * 16 + col) * 32 + quad * 8);

    float* ts = &Ts[wave][0];
    const int vv = v0 + lane;
    const bool vok = (vv < NUM_VERTS);

    for (int nt = wave; nt < 32; nt += 4) {
        const int b = b0 + nt;
        float* orow = out + (size_t)b * NUM_COORDS + (size_t)vv * 3;
        float h0 = 0.f, h1 = 0.f, h2 = 0.f;
        if (vok) { h0 = orow[0]; h1 = orow[1]; h2 = orow[2]; }

        const short8 bh = *(const short8*)(ahi + ((size_t)b * 16 + col) * 32 + quad * 8);
        const short8 bl = *(const short8*)(alo + ((size_t)b * 16 + col) * 32 + quad * 8);

        f32x4 acc[4];
        #pragma unroll
        for (int mt = 0; mt < 4; ++mt) {
            f32x4 z = {0.f, 0.f, 0.f, 0.f};
            z = __builtin_amdgcn_mfma_f32_16x16x32_bf16(wfrag[mt], bh, z, 0, 0, 0);
            z = __builtin_amdgcn_mfma_f32_16x16x32_bf16(wfrag[mt], bl, z, 0, 0, 0);
            acc[mt] = z;
        }
        #pragma unroll
        for (int mt = 0; mt < 4; ++mt)
            #pragma unroll
            for (int r = 0; r < 4; ++r)
                ts[(mt * 16 + quad * 4 + r) * 17 + col] = acc[mt][r];

        float Tp[12];
        #pragma unroll
        for (int i = 0; i < 12; ++i) Tp[i] = ts[lane * 17 + i];

        if (vok) {
            const float o0 = Tp[0] * h0 + Tp[1] * h1 + Tp[2]  * h2 + Tp[3];
            const float o1 = Tp[4] * h0 + Tp[5] * h1 + Tp[6]  * h2 + Tp[7];
            const float o2 = Tp[8] * h0 + Tp[9] * h1 + Tp[10] * h2 + Tp[11];
            orow[0] = o0; orow[1] = o1; orow[2] = o2;
        }
    }
}

extern "C" void kernel_launch(void* const* d_in, const int* in_sizes, int n_in,
                              void* d_out, int out_size, void* d_ws, size_t ws_size,
                              hipStream_t stream) {
    const float* x  = (const float*)d_in[0];
    const float* vt = (const float*)d_in[1];
    const float* sd = (const float*)d_in[2];
    const float* Jr = (const float*)d_in[3];
    const float* pd = (const float*)d_in[4];
    const float* w  = (const float*)d_in[5];
    const int* parents = (const int*)d_in[6];
    float* out = (float*)d_out;
    float* ws  = (float*)d_ws;
    unsigned short* xbf  = (unsigned short*)(ws + WS_XBF);
    unsigned short* dbf  = (unsigned short*)(ws + WS_DBF);
    unsigned short* whbf = (unsigned short*)(ws + WS_WHBF);
    unsigned short* ahi  = (unsigned short*)(ws + WS_AH);
    unsigned short* alo  = (unsigned short*)(ws + WS_AL);
    float* jrT = ws + WS_JRT;

    prep_vert  <<<27, 256, 0, stream>>>(Jr, w, jrT, whbf);
    convert_dbf<<<81, 256, 0, stream>>>(sd, pd, dbf);
    reduce_sj  <<<dim3(33, 24), 256, 0, stream>>>(jrT, sd, vt, ws);
    per_batch  <<<BATCH, 64, 0, stream>>>(x, parents, ws, ahi, alo, xbf);
    gemm_mfma  <<<dim3(323, 4), 256, 0, stream>>>(dbf, xbf, vt, out);
    skin_mfma  <<<dim3(108, 16), 256, 0, stream>>>(whbf, ahi, alo, out);
}